// Round 11
// baseline (350.300 us; speedup 1.0000x reference)
//
#include <hip/hip_runtime.h>
#include <stdint.h>

#define BATCH 4096
#define DIN 1024
#define DOUT 1024
#define NC 11          // GRID_SIZE + SPLINE_ORDER
#define KD 12288       // DIN * (1 + NC)
#define NKNOTS 15      // GRID_SIZE + 2*SPLINE_ORDER + 1

typedef __bf16 bf16x8 __attribute__((ext_vector_type(8)));
typedef float f32x4 __attribute__((ext_vector_type(4)));

__device__ __forceinline__ unsigned short f2bf(float f) {
    unsigned int u = __float_as_uint(f);
    unsigned int r = (u + 0x7FFFu + ((u >> 16) & 1u)) >> 16;
    return (unsigned short)r;
}

// ---------------------------------------------------------------------------
// Build A[b,:] = [ silu(x[b,:]) | bsplines(silu(x[b,:])) ] in bf16.
// (Previous-layer split-K accumulation now happens via atomics in gemm, so
// xin is already the complete layer input.)
// ---------------------------------------------------------------------------
__global__ __launch_bounds__(256) void build_A(
    const float* __restrict__ x, const float* __restrict__ grid,
    unsigned short* __restrict__ A) {
    __shared__ __align__(16) unsigned short lbs[256 * NC];
    const int tid = threadIdx.x;
    const int b  = blockIdx.x >> 2;
    const int i0 = (blockIdx.x & 3) * 256;
    const int i  = i0 + tid;

    float g[NKNOTS];
#pragma unroll
    for (int j = 0; j < NKNOTS; ++j) g[j] = grid[j];

    const float xv = x[(size_t)b * DIN + i];
    const float s  = xv / (1.f + __expf(-xv));   // silu

    float bs[14];
#pragma unroll
    for (int c = 0; c < 14; ++c) bs[c] = (s >= g[c] && s < g[c + 1]) ? 1.f : 0.f;
#pragma unroll
    for (int k = 1; k <= 3; ++k) {
        const float inv = (k == 1) ? 4.f : (k == 2) ? 2.f : (4.f / 3.f);
#pragma unroll
        for (int c = 0; c < 14 - k; ++c) {
            float left  = (s - g[c]) * inv;
            float right = (g[c + k + 1] - s) * inv;
            bs[c] = left * bs[c] + right * bs[c + 1];
        }
    }

    A[(size_t)b * KD + i] = f2bf(s);
#pragma unroll
    for (int c = 0; c < NC; ++c) lbs[tid * NC + c] = f2bf(bs[c]);
    __syncthreads();

    const uint4* src = (const uint4*)lbs;
    uint4* dst = (uint4*)(A + (size_t)b * KD + DIN + (size_t)i0 * NC);
    for (int j = tid; j < 352; j += 256) dst[j] = src[j];
}

// ---------------------------------------------------------------------------
// Build W[o, :] = [ base_w[o,:] | spline_w[o,:,:]*scaler[o,:] ] in bf16
// ---------------------------------------------------------------------------
__global__ __launch_bounds__(256) void build_W(
    const float* __restrict__ base_w, const float* __restrict__ spline_w,
    const float* __restrict__ scaler, unsigned short* __restrict__ W) {
    __shared__ __align__(16) unsigned short lw[256 * NC];
    const int tid = threadIdx.x;
    const int o  = blockIdx.x >> 2;
    const int i0 = (blockIdx.x & 3) * 256;
    const int i  = i0 + tid;
    const size_t oi = (size_t)o * DIN + i;

    const float sc = scaler[oi];
    W[(size_t)o * KD + i] = f2bf(base_w[oi]);
    const float* sw = spline_w + oi * NC;
#pragma unroll
    for (int c = 0; c < NC; ++c) lw[tid * NC + c] = f2bf(sw[c] * sc);
    __syncthreads();

    const uint4* src = (const uint4*)lw;
    uint4* dst = (uint4*)(W + (size_t)o * KD + DIN + (size_t)i0 * NC);
    for (int j = tid; j < 352; j += 256) dst[j] = src[j];
}

// ---------------------------------------------------------------------------
// GEMM (split-K=4, atomic accumulate): Out += A[4096,12288] @ W[1024,12288]^T.
// EXACT R8 schedule (best measured: 102us, MfmaUtil 41.6): 256x256 tile,
// BK=64, 8 waves (2m x 4n) of 128x64; m201-style 4-phase K-tile {ds-load
// changing operand; stage ONE half-tile; barrier; lgkmcnt(0); setprio; 16
// MFMA; setprio; barrier}; counted vmcnt(4)/vmcnt(2) before the ph2/ph4
// closing barriers (every publication wait covers multi-phase-old loads).
// Staging spread one half-tile per phase — R9/R10 proved bunching all 8
// regresses ~10% (LDS write-port burst collides with ds_read bursts).
// T2 XOR-swizzle (conflicts 0). n-grouped block map (A panel L2-shared,
// FETCH 74MB). Epilogue: unsafeAtomicAdd into zeroed Out (all ksp blocks).
// ---------------------------------------------------------------------------
#define BM 256
#define BN 256
#define BK 64
#define KSPL 4
#define KTPER 48

#define LOADAF(AF, BASE)                                                       \
    _Pragma("unroll")                                                          \
    for (int fm = 0; fm < 4; ++fm)                                             \
        _Pragma("unroll")                                                      \
        for (int ks = 0; ks < 2; ++ks)                                         \
            AF[fm][ks] = *(const bf16x8*)&(BASE)[(wm * 64 + fm * 16 + rof) * 64 + \
                                                 (((ks * 4 + kcol) ^ xr) * 8)];

#define LOADBF(BF, BASE)                                                       \
    _Pragma("unroll")                                                          \
    for (int fn = 0; fn < 2; ++fn)                                             \
        _Pragma("unroll")                                                      \
        for (int ks = 0; ks < 2; ++ks)                                         \
            BF[fn][ks] = *(const bf16x8*)&(BASE)[(wn * 32 + fn * 16 + rof) * 64 + \
                                                 (((ks * 4 + kcol) ^ xr) * 8)];

#define MFMA16(AF, BF, RO, CO)                                                 \
    __builtin_amdgcn_s_setprio(1);                                             \
    _Pragma("unroll")                                                          \
    for (int ks = 0; ks < 2; ++ks)                                             \
        _Pragma("unroll")                                                      \
        for (int fm = 0; fm < 4; ++fm)                                         \
            _Pragma("unroll")                                                  \
            for (int fn = 0; fn < 2; ++fn)                                     \
                acc[(RO) + fm][(CO) + fn] =                                    \
                    __builtin_amdgcn_mfma_f32_16x16x32_bf16(                   \
                        AF[fm][ks], BF[fn][ks], acc[(RO) + fm][(CO) + fn], 0, 0, 0); \
    __builtin_amdgcn_s_setprio(0);

#define SBAR  __builtin_amdgcn_s_barrier()
#define SCHED __builtin_amdgcn_sched_barrier(0)

__global__ __launch_bounds__(512, 2) void gemm_kan(
    const unsigned short* __restrict__ A,
    const unsigned short* __restrict__ W,
    float* __restrict__ Out) {
    __shared__ unsigned short As[2 * 2 * 8192];   // [buf][half][128*64] = 64KB
    __shared__ unsigned short Bs[2 * 2 * 8192];   // 64KB (128KB total)

    const int tid  = threadIdx.x;
    const int wave = tid >> 6;
    const int lane = tid & 63;
    const int per = 16 * KSPL;                   // blocks per n-tile
    const int n0  = (blockIdx.x / per) * BN;
    const int r   = blockIdx.x % per;
    const int ksp = r % KSPL;
    const int m0  = (r / KSPL) * BM;
    const int wm = wave >> 2;                    // 0..1
    const int wn = wave & 3;                     // 0..3

    // staging: linear LDS dest (lane*16B); global source col pre-swizzled so
    // LDS[row][c'] holds global col c' ^ ((row&7)<<4)  (T2, rule #21)
    const int srow = lane >> 3;
    const int scol = 8 * ((lane & 7) ^ (lane >> 3));
    const int kbase = ksp * KTPER * BK;

    f32x4 acc[8][4];
#pragma unroll
    for (int a = 0; a < 8; ++a)
#pragma unroll
        for (int b = 0; b < 4; ++b) acc[a][b] = (f32x4){0.f, 0.f, 0.f, 0.f};

    auto stageA = [&](int buf, int h, int kt) {
        const int kk = kbase + kt * BK + scol;
#pragma unroll
        for (int c = 0; c < 2; ++c) {
            const int chunk = wave * 2 + c;      // 0..15 (8-row chunks in half)
            const unsigned short* ga =
                A + (size_t)(m0 + h * 128 + chunk * 8 + srow) * KD + kk;
            __builtin_amdgcn_global_load_lds(
                (const __attribute__((address_space(1))) unsigned int*)ga,
                (__attribute__((address_space(3))) unsigned int*)
                    &As[buf * 16384 + h * 8192 + chunk * 512], 16, 0, 0);
        }
    };
    auto stageB = [&](int buf, int h, int kt) {
        const int kk = kbase + kt * BK + scol;
#pragma unroll
        for (int c = 0; c < 2; ++c) {
            const int chunk = wave * 2 + c;
            const unsigned short* gb =
                W + (size_t)(n0 + h * 128 + chunk * 8 + srow) * KD + kk;
            __builtin_amdgcn_global_load_lds(
                (const __attribute__((address_space(1))) unsigned int*)gb,
                (__attribute__((address_space(3))) unsigned int*)
                    &Bs[buf * 16384 + h * 8192 + chunk * 512], 16, 0, 0);
        }
    };

    // prologue: tile 0 (order Bh0,Bh1,Ah0,Ah1); retire first 3 halves; barrier.
    stageB(0, 0, 0); stageB(0, 1, 0); stageA(0, 0, 0); stageA(0, 1, 0);
    asm volatile("s_waitcnt vmcnt(2)" ::: "memory");
    SBAR;

    const int rof  = lane & 15;
    const int xr   = lane & 7;
    const int kcol = lane >> 4;

    bf16x8 af[4][2], b0[2][2], b1[2][2];

    for (int t = 0; t < KTPER; ++t) {
        const int cur = t & 1;
        const int nxt = cur ^ 1;
        const bool pf = (t + 1 < KTPER);
        const unsigned short* Ab = &As[cur * 16384];
        const unsigned short* Bb = &Bs[cur * 16384];

        // ---- ph1: quadrant (H0,F0); loads 12; stage Bh0(t+1)
        LOADAF(af, Ab);
        LOADBF(b0, Bb);
        if (pf) stageB(nxt, 0, t + 1);
        asm volatile("s_waitcnt lgkmcnt(8)" ::: "memory");
        SBAR;
        asm volatile("s_waitcnt lgkmcnt(0)" ::: "memory");
        SCHED;
        MFMA16(af, b0, 0, 0);
        SCHED;
        SBAR;

        // ---- ph2: (H0,F1); loads 4; stage Bh1(t+1); vmcnt(4) covers Ah1(t)
        LOADBF(b1, Bb + 8192);
        if (pf) stageB(nxt, 1, t + 1);
        SBAR;
        asm volatile("s_waitcnt lgkmcnt(0)" ::: "memory");
        SCHED;
        MFMA16(af, b1, 0, 2);
        SCHED;
        if (pf) { asm volatile("s_waitcnt vmcnt(4)" ::: "memory"); }
        else    { asm volatile("s_waitcnt vmcnt(0)" ::: "memory"); }
        SBAR;

        // ---- ph3: (H1,F1); loads 8; stage Ah0(t+1)
        LOADAF(af, Ab + 8192);
        if (pf) stageA(nxt, 0, t + 1);
        SBAR;
        asm volatile("s_waitcnt lgkmcnt(0)" ::: "memory");
        SCHED;
        MFMA16(af, b1, 4, 2);
        SCHED;
        SBAR;

        // ---- ph4: (H1,F0); zero ds-loads; stage Ah1(t+1); vmcnt(2) covers
        // Bh0,Bh1,Ah0 of t+1 for the next ph1/ph2 reads.
        if (pf) stageA(nxt, 1, t + 1);
        SBAR;
        SCHED;
        MFMA16(af, b0, 4, 0);
        SCHED;
        if (pf) { asm volatile("s_waitcnt vmcnt(2)" ::: "memory"); }
        SBAR;
    }

    // epilogue: C/D layout col=lane&15, row=(lane>>4)*4+reg.
    // Atomic accumulate (Out zeroed by memset; all KSPL blocks add).
    const int crow = (lane >> 4) * 4;
    const int ccol = lane & 15;
#pragma unroll
    for (int H = 0; H < 2; ++H)
#pragma unroll
        for (int fm = 0; fm < 4; ++fm)
#pragma unroll
            for (int F = 0; F < 2; ++F)
#pragma unroll
                for (int fn = 0; fn < 2; ++fn) {
                    const int row = m0 + H * 128 + wm * 64 + fm * 16 + crow;
                    const int col = n0 + F * 128 + wn * 32 + fn * 16 + ccol;
#pragma unroll
                    for (int rr = 0; rr < 4; ++rr)
                        unsafeAtomicAdd(&Out[(size_t)(row + rr) * DOUT + col],
                                        acc[H * 4 + fm][F * 2 + fn][rr]);
                }
}

// ---------------------------------------------------------------------------
extern "C" void kernel_launch(void* const* d_in, const int* in_sizes, int n_in,
                              void* d_out, int out_size, void* d_ws, size_t ws_size,
                              hipStream_t stream) {
    const float* x        = (const float*)d_in[0];
    const float* base_w   = (const float*)d_in[1];
    const float* spline_w = (const float*)d_in[2];
    const float* scaler   = (const float*)d_in[3];
    const float* grid     = (const float*)d_in[4];
    float* out = (float*)d_out;

    char* ws = (char*)d_ws;
    unsigned short* Abf = (unsigned short*)ws;                       // 100,663,296 B
    unsigned short* Wbf = (unsigned short*)(ws + 100663296);         //  25,165,824 B
    float* xtmp = (float*)(ws + 100663296 + 25165824);               //  16,777,216 B

    // zero the atomic-accumulate destinations (capturable async memsets)
    hipMemsetAsync(xtmp, 0, (size_t)BATCH * DOUT * 4, stream);
    hipMemsetAsync(out,  0, (size_t)BATCH * DOUT * 4, stream);

    for (int layer = 0; layer < 2; ++layer) {
        const float* xin = (layer == 0) ? x : xtmp;
        float* xout      = (layer == 0) ? xtmp : out;
        build_W<<<4096, 256, 0, stream>>>(base_w + (size_t)layer * DOUT * DIN,
                                          spline_w + (size_t)layer * DOUT * DIN * NC,
                                          scaler + (size_t)layer * DOUT * DIN, Wbf);
        build_A<<<16384, 256, 0, stream>>>(xin, grid, Abf);
        gemm_kan<<<64 * KSPL, 512, 0, stream>>>(Abf, Wbf, xout);
    }
}